// Round 7
// baseline (451.914 us; speedup 1.0000x reference)
//
#include <hip/hip_runtime.h>

// Problem geometry (fixed by the reference).
#define NFRAMES 64
#define HH 1024
#define WW 1024

typedef float f32x4 __attribute__((ext_vector_type(4)));

// JAX map_coordinates mode='mirror' index fixer: |((idx + s) mod 2s) - s|,
// s = size-1, applied to the INTEGER corner indices (floor(c) and floor(c)+1).
__device__ __forceinline__ int mirror_fix(int idx, int s, int m) {
    int t = (idx + s) % m;
    if (t < 0) t += m;
    t -= s;
    return t < 0 ? -t : t;
}

// Fully-static interior patch compute: 5x2 float4 window -> 4x4 outputs.
// O = frame-uniform sub-quad offset (kx & 3). All register indices static.
template<int O>
__device__ __forceinline__ void compute_patch(const f32x4 (&L)[5][2],
                                              float fy, float gy,
                                              float fx, float gx,
                                              float fl, float bi,
                                              f32x4 (&res)[4]) {
    float w[5][5];
    #pragma unroll
    for (int r = 0; r < 5; ++r) {
        #pragma unroll
        for (int c = 0; c < 5; ++c) {
            const int idx = O + c;                 // static 0..7
            w[r][c] = (idx < 4) ? L[r][0][idx & 3] : L[r][1][idx & 3];
        }
    }
    #pragma unroll
    for (int r = 0; r < 4; ++r) {
        float t[5];
        #pragma unroll
        for (int c = 0; c < 5; ++c) t[c] = gy * w[r][c] + fy * w[r + 1][c];
        res[r][0] = (gx * t[0] + fx * t[1]) * fl + bi;
        res[r][1] = (gx * t[1] + fx * t[2]) * fl + bi;
        res[r][2] = (gx * t[2] + fx * t[3]) * fl + bi;
        res[r][3] = (gx * t[3] + fx * t[4]) * fl + bi;
    }
}

__global__ __launch_bounds__(256) void
flux_shift_kernel(const float* __restrict__ in,    // [N, H, W]
                  const float* __restrict__ flux,  // [N]
                  const float* __restrict__ noise, // [N]
                  const float* __restrict__ dydx,  // [N, 2]
                  float* __restrict__ out) {       // [N, H, W]
    // Bijective XCD swizzle (16384 blocks, 8 XCDs, 16384%8==0): XCD x
    // processes work indices [2048x, 2048x+2048) = 8 contiguous frames,
    // band-sequential -> boundary-row reuse is a same-XCD L2 hit.
    const int bid = blockIdx.x;
    const int swz = ((bid & 7) << 11) | (bid >> 3);
    const int band = swz & 255;
    const int n    = swz >> 8;               // block-uniform -> scalar
    const int y0   = band << 2;
    const int x    = threadIdx.x << 2;       // first output col of this thread

    // Frame params (uniform n -> s_load).
    const float dy = dydx[2 * n];
    const float dx = dydx[2 * n + 1];
    const float fl = flux[n];
    const float bi = noise[n];

    const float nky = floorf(-dy);
    const float nkx = floorf(-dx);
    const float fy = -dy - nky;              // frame-constant fractions
    const float fx = -dx - nkx;
    const int ky = (int)nky;
    const int kx = (int)nkx;
    const float gy = 1.0f - fy;
    const float gx = 1.0f - fx;

    const int ry = y0 + ky;                  // need input rows ry..ry+4
    const int o  = kx & 3;                   // frame-uniform select offset
    const int A  = x + kx - o;               // 16B-aligned window, cols A..A+7

    const float* __restrict__ base = in + (size_t)n * (HH * WW);
    float* __restrict__ ob = out + (size_t)n * (HH * WW) + (size_t)y0 * WW + x;

    if (ry >= 0 && ry + 4 <= HH - 1 && A >= 0 && A <= WW - 8) {
        // Interior fast path: 10 independent aligned float4 loads (deep MLP).
        const float* __restrict__ p = base + (size_t)ry * WW + A;
        f32x4 L[5][2];
        #pragma unroll
        for (int r = 0; r < 5; ++r) {
            L[r][0] = *reinterpret_cast<const f32x4*>(p + (size_t)r * WW);
            L[r][1] = *reinterpret_cast<const f32x4*>(p + (size_t)r * WW + 4);
        }
        f32x4 res[4];
        switch (o) {  // block-uniform: one scalar branch, all-static bodies
            case 0:  compute_patch<0>(L, fy, gy, fx, gx, fl, bi, res); break;
            case 1:  compute_patch<1>(L, fy, gy, fx, gx, fl, bi, res); break;
            case 2:  compute_patch<2>(L, fy, gy, fx, gx, fl, bi, res); break;
            default: compute_patch<3>(L, fy, gy, fx, gx, fl, bi, res); break;
        }
        // Output is never re-read: nontemporal stores keep L2/L3 for input.
        #pragma unroll
        for (int r = 0; r < 4; ++r)
            __builtin_nontemporal_store(res[r],
                reinterpret_cast<f32x4*>(ob + (size_t)r * WW));
    } else {
        // Border path: full mirror fixing per corner index, per output row.
        const int sh = HH - 1, mh = 2 * sh;
        const int sw = WW - 1, mw = 2 * sw;
        const int cx0 = x + kx;
        #pragma unroll
        for (int r = 0; r < 4; ++r) {
            const int iy0 = mirror_fix(y0 + r + ky,     sh, mh);
            const int iy1 = mirror_fix(y0 + r + ky + 1, sh, mh);
            const float* __restrict__ r0 = base + (size_t)iy0 * WW;
            const float* __restrict__ r1 = base + (size_t)iy1 * WW;
            f32x4 res;
            #pragma unroll
            for (int j = 0; j < 4; ++j) {
                const int c0 = mirror_fix(cx0 + j,     sw, mw);
                const int c1 = mirror_fix(cx0 + j + 1, sw, mw);
                const float t0 = gy * r0[c0] + fy * r1[c0];
                const float t1 = gy * r0[c1] + fy * r1[c1];
                res[j] = (gx * t0 + fx * t1) * fl + bi;
            }
            __builtin_nontemporal_store(res,
                reinterpret_cast<f32x4*>(ob + (size_t)r * WW));
        }
    }
}

extern "C" void kernel_launch(void* const* d_in, const int* in_sizes, int n_in,
                              void* d_out, int out_size, void* d_ws, size_t ws_size,
                              hipStream_t stream) {
    const float* in    = (const float*)d_in[0]; // [1, N, H, W, 1]
    const float* flux  = (const float*)d_in[1]; // [N,1,1,1]
    const float* noise = (const float*)d_in[2]; // [N,1,1,1]
    const float* dydx  = (const float*)d_in[3]; // [N,2]
    float* out = (float*)d_out;

    // 64 frames x 256 bands (4 rows each) = 16384 blocks, single-shot.
    const int grid  = NFRAMES * (HH / 4);
    const int block = 256;

    flux_shift_kernel<<<grid, block, 0, stream>>>(in, flux, noise, dydx, out);
}

// Round 8
// 449.576 us; speedup vs baseline: 1.0052x; 1.0052x over previous
//
#include <hip/hip_runtime.h>

// Problem geometry (fixed by the reference).
#define NFRAMES 64
#define HH 1024
#define WW 1024
#define CHUNK 64            // output rows per block
#define SH (HH - 1)
#define SW (WW - 1)

typedef float f32x4 __attribute__((ext_vector_type(4)));

// mirror index fix, valid for -s <= i <= 2s (single reflection each side).
__device__ __forceinline__ int reflect(int i, int s) {
    if (i < 0) i = -i;
    if (i > s) i = 2 * s - i;
    return i;
}

// Static 5-wide window extraction from an aligned 8-float pair. O in [0,3].
template<int O>
__device__ __forceinline__ void extract5(const f32x4 a, const f32x4 b, float (&w)[5]) {
#pragma unroll
    for (int c = 0; c < 5; ++c) {
        const int idx = O + c;                      // static 0..7
        w[c] = (idx < 4) ? a[idx] : b[idx - 4];
    }
}

// Rolling column-walk over CHUNK rows with a 4-deep register ring,
// prefetch distance 4. Each input row loaded once per block.
template<int O>
__device__ __forceinline__ void run_chunk(const float* __restrict__ fin,
                                          float* __restrict__ fout,
                                          int y0, int ky, int A,
                                          float fy, float gy,
                                          float Gx, float Fx, float bi) {
    const int x  = threadIdx.x << 2;
    const int rb = y0 + ky;                         // input row of rel-row 0

    f32x4 r0a, r0b, r1a, r1b, r2a, r2b, r3a, r3b;
    {   // prologue: rel rows 0..3
        const float* p0 = fin + (size_t)reflect(rb + 0, SH) * WW;
        const float* p1 = fin + (size_t)reflect(rb + 1, SH) * WW;
        const float* p2 = fin + (size_t)reflect(rb + 2, SH) * WW;
        const float* p3 = fin + (size_t)reflect(rb + 3, SH) * WW;
        r0a = *(const f32x4*)(p0 + A); r0b = *(const f32x4*)(p0 + A + 4);
        r1a = *(const f32x4*)(p1 + A); r1b = *(const f32x4*)(p1 + A + 4);
        r2a = *(const f32x4*)(p2 + A); r2b = *(const f32x4*)(p2 + A + 4);
        r3a = *(const f32x4*)(p3 + A); r3b = *(const f32x4*)(p3 + A + 4);
    }

#define SUBITER(J, LOA, LOB, HIA, HIB, PF)                                     \
    {                                                                          \
        float wl[5], wh[5];                                                    \
        extract5<O>(LOA, LOB, wl);                                             \
        extract5<O>(HIA, HIB, wh);                                             \
        if (PF) { /* prefetch rel row (J)+4 into the just-freed lower slot */  \
            const float* pp = fin + (size_t)reflect(rb + (J) + 4, SH) * WW;    \
            LOA = *(const f32x4*)(pp + A);                                     \
            LOB = *(const f32x4*)(pp + A + 4);                                 \
        }                                                                      \
        const float t0 = gy * wl[0] + fy * wh[0];                              \
        const float t1 = gy * wl[1] + fy * wh[1];                              \
        const float t2 = gy * wl[2] + fy * wh[2];                              \
        const float t3 = gy * wl[3] + fy * wh[3];                              \
        const float t4 = gy * wl[4] + fy * wh[4];                              \
        f32x4 ov;                                                              \
        ov[0] = fmaf(Gx, t0, fmaf(Fx, t1, bi));                                \
        ov[1] = fmaf(Gx, t1, fmaf(Fx, t2, bi));                                \
        ov[2] = fmaf(Gx, t2, fmaf(Fx, t3, bi));                                \
        ov[3] = fmaf(Gx, t3, fmaf(Fx, t4, bi));                                \
        *(f32x4*)(fout + (size_t)(y0 + (J)) * WW + x) = ov;                    \
    }

    int j = 0;
    for (int m = 0; m < CHUNK / 4 - 1; ++m, j += 4) {
        SUBITER(j + 0, r0a, r0b, r1a, r1b, true)
        SUBITER(j + 1, r1a, r1b, r2a, r2b, true)
        SUBITER(j + 2, r2a, r2b, r3a, r3b, true)
        SUBITER(j + 3, r3a, r3b, r0a, r0b, true)
    }
    // tail macro: only j+0 still needs a prefetch (rel row 64 -> slot 0)
    SUBITER(j + 0, r0a, r0b, r1a, r1b, true)
    SUBITER(j + 1, r1a, r1b, r2a, r2b, false)
    SUBITER(j + 2, r2a, r2b, r3a, r3b, false)
    SUBITER(j + 3, r3a, r3b, r0a, r0b, false)
#undef SUBITER
}

__global__ __launch_bounds__(256) void
flux_shift_kernel(const float* __restrict__ in,    // [N, H, W]
                  const float* __restrict__ flux,  // [N]
                  const float* __restrict__ noise, // [N]
                  const float* __restrict__ dydx,  // [N, 2]
                  float* __restrict__ out) {       // [N, H, W]
    const int chunk = blockIdx.x & (HH / CHUNK - 1);   // 16 chunks/frame
    const int n     = blockIdx.x >> 4;                 // block-uniform
    const int y0    = chunk * CHUNK;

    // Frame params (uniform n -> scalar loads).
    const float dy = dydx[2 * n];
    const float dx = dydx[2 * n + 1];
    const float fl = flux[n];
    const float bi = noise[n];

    const float nky = floorf(-dy);
    const float nkx = floorf(-dx);
    const float fy = -dy - nky;              // frame-constant fractions
    const float fx = -dx - nkx;
    const int ky = (int)nky;
    const int kx = (int)nkx;
    const float gy = 1.0f - fy;
    const float gx = 1.0f - fx;
    const float Gx = gx * fl, Fx = fx * fl;  // fold flux into weights

    const int x = threadIdx.x << 2;
    const int o = kx & 3;                    // frame-uniform select offset
    int A = x + kx - o;                      // 16B-aligned window start
    A = A < 0 ? 0 : (A > WW - 8 ? WW - 8 : A);  // clamp; edges fixed up below

    const float* __restrict__ fin  = in  + (size_t)n * (HH * WW);
    float* __restrict__       fout = out + (size_t)n * (HH * WW);

    switch (o) {  // block-uniform: one scalar branch, all-static bodies
        case 0:  run_chunk<0>(fin, fout, y0, ky, A, fy, gy, Gx, Fx, bi); break;
        case 1:  run_chunk<1>(fin, fout, y0, ky, A, fy, gy, Gx, Fx, bi); break;
        case 2:  run_chunk<2>(fin, fout, y0, ky, A, fy, gy, Gx, Fx, bi); break;
        default: run_chunk<3>(fin, fout, y0, ky, A, fy, gy, Gx, Fx, bi); break;
    }

    // Order main stores before edge overwrites (different threads, same addrs).
    __syncthreads();

    // Fixup phase: recompute the 6 edge quads per row (cols where A may have
    // been clamped) with exact mirror handling. Covers |kx| <= 12. Data is
    // L2-warm (rows just streamed). 384 items, 256 threads -> <=2 each.
    for (int f = threadIdx.x; f < CHUNK * 6; f += 256) {
        const int rr = f / 6;
        const int qe = f - rr * 6;
        const int q  = qe < 3 ? qe : 250 + qe;   // quads {0,1,2,253,254,255}
        const int yy = y0 + rr;
        const float* __restrict__ p0 = fin + (size_t)reflect(yy + ky,     SH) * WW;
        const float* __restrict__ p1 = fin + (size_t)reflect(yy + ky + 1, SH) * WW;
        const int cx0 = (q << 2) + kx;
        f32x4 ov;
        #pragma unroll
        for (int jj = 0; jj < 4; ++jj) {
            const int c0 = reflect(cx0 + jj,     SW);
            const int c1 = reflect(cx0 + jj + 1, SW);
            const float t0 = gy * p0[c0] + fy * p1[c0];
            const float t1 = gy * p0[c1] + fy * p1[c1];
            ov[jj] = fmaf(Gx, t0, fmaf(Fx, t1, bi));
        }
        *(f32x4*)(fout + (size_t)yy * WW + (q << 2)) = ov;
    }
}

extern "C" void kernel_launch(void* const* d_in, const int* in_sizes, int n_in,
                              void* d_out, int out_size, void* d_ws, size_t ws_size,
                              hipStream_t stream) {
    const float* in    = (const float*)d_in[0]; // [1, N, H, W, 1]
    const float* flux  = (const float*)d_in[1]; // [N,1,1,1]
    const float* noise = (const float*)d_in[2]; // [N,1,1,1]
    const float* dydx  = (const float*)d_in[3]; // [N,2]
    float* out = (float*)d_out;

    // 64 frames x 16 chunks (64 rows each) = 1024 blocks, 4 blocks/CU.
    const int grid  = NFRAMES * (HH / CHUNK);
    const int block = 256;

    flux_shift_kernel<<<grid, block, 0, stream>>>(in, flux, noise, dydx, out);
}